// Round 1
// baseline (919.023 us; speedup 1.0000x reference)
//
#include <hip/hip_runtime.h>
#include <hip/hip_bf16.h>
#include <math.h>

typedef short bf16x8 __attribute__((ext_vector_type(8)));
typedef float f32x4 __attribute__((ext_vector_type(4)));
typedef unsigned short u16;

#define N_TOK  4096
#define D_IN   512
#define D_ATTN 64
#define NBUCK  4096
#define CAP    2048
#define TOPP   0.9f
#define LN_EPS 1e-5f

__device__ __forceinline__ u16 f2bf(float f) {
  unsigned int u = __float_as_uint(f);
  return (u16)((u + 0x7FFFu + ((u >> 16) & 1u)) >> 16);
}

// ---------------------------------------------------------------------------
// Generic MFMA GEMM: C = rowmap(A) @ B^T
//   A: bf16 [M][K] row-major (lda), B: bf16 [Nc][K] row-major (ldb)
//   block tile 64x64, 4 waves (2x2), wave tile 32x32 = 2x2 mfma_16x16x32
// EPI: 0 store f32; 1 tanh->bf16; 2 bf16; 3 f32 +=; 4 bf16 dual (C and C^T)
// SMODE: 0 identity; 1 row->max(row-shift,0); 2 row->min(row+shift,amax)
// ---------------------------------------------------------------------------
template<int EPI, int SMODE>
__global__ __launch_bounds__(256)
void gemm_abt(const u16* __restrict__ A, int lda, int amax, int shift,
              const u16* __restrict__ B, int ldb, int K,
              float* __restrict__ Cf, u16* __restrict__ Cb,
              u16* __restrict__ CbT, int ldc, int ldct)
{
  const int tid  = threadIdx.x;
  const int wave = tid >> 6;
  const int lane = tid & 63;
  const int l15  = lane & 15;
  const int l4   = lane >> 4;          // 0..3
  const int brow = blockIdx.y << 6;
  const int bcol = blockIdx.x << 6;
  const int wr   = (wave >> 1) << 5;
  const int wc   = (wave & 1) << 5;

  const u16* Ap[2];
  const u16* Bp[2];
#pragma unroll
  for (int m = 0; m < 2; ++m) {
    int r = brow + wr + m * 16 + l15;
    if (SMODE == 1) { r = r - shift; if (r < 0) r = 0; }
    if (SMODE == 2) { r = r + shift; if (r > amax) r = amax; }
    Ap[m] = A + (size_t)r * lda + l4 * 8;
    int c = bcol + wc + m * 16 + l15;
    Bp[m] = B + (size_t)c * ldb + l4 * 8;
  }

  f32x4 acc[2][2];
#pragma unroll
  for (int m = 0; m < 2; ++m)
#pragma unroll
    for (int n = 0; n < 2; ++n) {
      acc[m][n][0] = 0.f; acc[m][n][1] = 0.f; acc[m][n][2] = 0.f; acc[m][n][3] = 0.f;
    }

  for (int k0 = 0; k0 < K; k0 += 32) {
    bf16x8 a0 = *(const bf16x8*)(Ap[0] + k0);
    bf16x8 a1 = *(const bf16x8*)(Ap[1] + k0);
    bf16x8 b0 = *(const bf16x8*)(Bp[0] + k0);
    bf16x8 b1 = *(const bf16x8*)(Bp[1] + k0);
    acc[0][0] = __builtin_amdgcn_mfma_f32_16x16x32_bf16(a0, b0, acc[0][0], 0, 0, 0);
    acc[0][1] = __builtin_amdgcn_mfma_f32_16x16x32_bf16(a0, b1, acc[0][1], 0, 0, 0);
    acc[1][0] = __builtin_amdgcn_mfma_f32_16x16x32_bf16(a1, b0, acc[1][0], 0, 0, 0);
    acc[1][1] = __builtin_amdgcn_mfma_f32_16x16x32_bf16(a1, b1, acc[1][1], 0, 0, 0);
  }

#pragma unroll
  for (int m = 0; m < 2; ++m)
#pragma unroll
    for (int n = 0; n < 2; ++n)
#pragma unroll
      for (int r = 0; r < 4; ++r) {
        const int row = brow + wr + m * 16 + l4 * 4 + r;   // C/D: col=lane&15, row=(lane>>4)*4+r
        const int col = bcol + wc + n * 16 + l15;
        const float v = acc[m][n][r];
        if (EPI == 0) Cf[(size_t)row * ldc + col] = v;
        if (EPI == 1) Cb[(size_t)row * ldc + col] = f2bf(tanhf(v));
        if (EPI == 2) Cb[(size_t)row * ldc + col] = f2bf(v);
        if (EPI == 3) Cf[(size_t)row * ldc + col] += v;
        if (EPI == 4) {
          u16 hv = f2bf(v);
          Cb [(size_t)row * ldc  + col] = hv;
          CbT[(size_t)col * ldct + row] = hv;
        }
      }
}

// ---------------------------------------------------------------------------
// Nucleus (top-p) row kernel. In: f32 scores row. Out: bf16 A row written
// in-place over the same memory (first 8KB of the row's 16KB pitch).
// ---------------------------------------------------------------------------
__global__ __launch_bounds__(256)
void nucleus_kernel(float* S)
{
  const int row = blockIdx.x;
  const int tid = threadIdx.x;
  float* srow = S + (size_t)row * N_TOK;
  u16*   arow = (u16*)srow;            // bf16 view, effective lda = 2*N_TOK

  __shared__ float e[N_TOK];           // scores, then exp values
  __shared__ float hist[NBUCK];
  __shared__ unsigned char bclass[NBUCK];   // 0 drop, 1 keep, 2 boundary
  __shared__ unsigned char keepf[N_TOK];
  __shared__ float ge[CAP];
  __shared__ int   gcol[CAP];
  __shared__ float csum[256];
  __shared__ float red[8];
  __shared__ float s_smax, s_smin, s_E, s_den0, s_Abnd, s_keptb;
  __shared__ int   s_bstar, s_cnt;

  // ---- pass 0: load row, max/min
  float lmax = -3.402823466e38f, lmin = 3.402823466e38f;
  for (int j = tid; j < N_TOK; j += 256) {
    float v = srow[j];
    e[j] = v;
    lmax = fmaxf(lmax, v);
    lmin = fminf(lmin, v);
  }
  for (int o = 32; o; o >>= 1) { lmax = fmaxf(lmax, __shfl_xor(lmax, o)); lmin = fminf(lmin, __shfl_xor(lmin, o)); }
  if ((tid & 63) == 0) { red[tid >> 6] = lmax; red[4 + (tid >> 6)] = lmin; }
  __syncthreads();
  if (tid == 0) {
    float mx = red[0], mn = red[4];
    for (int w = 1; w < 4; ++w) { mx = fmaxf(mx, red[w]); mn = fminf(mn, red[4 + w]); }
    s_smax = mx; s_smin = mn; s_bstar = -1; s_cnt = 0; s_keptb = 0.f; s_Abnd = 0.f;
  }
  for (int b = tid; b < NBUCK; b += 256) hist[b] = 0.f;
  __syncthreads();

  const float smax = s_smax, smin = s_smin;
  const float emin  = __expf(smin - smax);
  const float scale = (float)NBUCK / fmaxf(1.0f - emin, 1e-30f);

  // ---- pass 1: exp, histogram (exp-mass on e-value buckets), E
  float lE = 0.f;
  for (int j = tid; j < N_TOK; j += 256) {
    float ev = __expf(e[j] - smax);
    e[j] = ev;
    lE += ev;
    int b = (int)((ev - emin) * scale);
    b = (b < 0) ? 0 : ((b > NBUCK - 1) ? NBUCK - 1 : b);
    atomicAdd(&hist[b], ev);
  }
  for (int o = 32; o; o >>= 1) lE += __shfl_xor(lE, o);
  if ((tid & 63) == 0) red[tid >> 6] = lE;
  __syncthreads();
  if (tid == 0) s_E = red[0] + red[1] + red[2] + red[3];
  __syncthreads();
  const float E = s_E;
  const float T = TOPP * E;

  // ---- pass 2: suffix scan over buckets (descending), classify
  float ch = 0.f;
  const int b0 = tid * 16;
  for (int b = b0; b < b0 + 16; ++b) ch += hist[b];
  csum[tid] = ch;
  __syncthreads();
  if (tid == 0) {
    float run = 0.f;
    for (int t = 255; t >= 0; --t) { float tmp = csum[t]; csum[t] = run; run += tmp; }
  }
  __syncthreads();
  float den0 = 0.f;
  float Arun = csum[tid];              // mass strictly above my chunk's top bucket
  for (int b = b0 + 15; b >= b0; --b) {
    float bm = hist[b];
    unsigned char c;
    if (Arun >= T) c = 0;
    else if (Arun + bm > T) { c = 2; s_bstar = b; s_Abnd = Arun; }
    else { c = 1; den0 += bm; }
    bclass[b] = c;
    Arun += bm;
  }
  for (int o = 32; o; o >>= 1) den0 += __shfl_xor(den0, o);
  if ((tid & 63) == 0) red[tid >> 6] = den0;
  __syncthreads();
  if (tid == 0) s_den0 = red[0] + red[1] + red[2] + red[3];
  __syncthreads();
  const int bstar = s_bstar;

  // ---- gather boundary-bucket elements
  if (bstar >= 0) {
    for (int j = tid; j < N_TOK; j += 256) {
      float ev = e[j];
      int b = (int)((ev - emin) * scale);
      b = (b < 0) ? 0 : ((b > NBUCK - 1) ? NBUCK - 1 : b);
      if (b == bstar) {
        int i = atomicAdd(&s_cnt, 1);
        if (i < CAP) { ge[i] = ev; gcol[i] = j; }
      }
    }
  }
  __syncthreads();
  const int cnt = s_cnt;

  // ---- refine boundary: exact prefix mass with stable-tie rule (idx order)
  float lk = 0.f;
  if (bstar >= 0) {
    const float Abnd = s_Abnd;
    if (cnt <= CAP) {
      for (int i = tid; i < cnt; i += 256) {
        float ei = ge[i]; int ci = gcol[i];
        float m = Abnd;
        for (int l = 0; l < cnt; ++l) {
          float el = ge[l];
          if (el > ei || (el == ei && gcol[l] < ci)) m += el;
        }
        unsigned char kp = (m < T) ? 1 : 0;
        keepf[ci] = kp;
        if (kp) lk += ei;
      }
    } else {
      // pathological fallback (near-degenerate rows): O(N * boundary)
      for (int j = tid; j < N_TOK; j += 256) {
        float ej = e[j];
        int b = (int)((ej - emin) * scale);
        b = (b < 0) ? 0 : ((b > NBUCK - 1) ? NBUCK - 1 : b);
        if (b != bstar) continue;
        float m = Abnd;
        for (int l = 0; l < N_TOK; ++l) {
          float el = e[l];
          int bl = (int)((el - emin) * scale);
          bl = (bl < 0) ? 0 : ((bl > NBUCK - 1) ? NBUCK - 1 : bl);
          if (bl == bstar && (el > ej || (el == ej && l < j))) m += el;
        }
        unsigned char kp = (m < T) ? 1 : 0;
        keepf[j] = kp;
        if (kp) lk += ej;
      }
    }
  }
  for (int o = 32; o; o >>= 1) lk += __shfl_xor(lk, o);
  if ((tid & 63) == 0) red[tid >> 6] = lk;
  __syncthreads();
  if (tid == 0) s_keptb = red[0] + red[1] + red[2] + red[3];
  __syncthreads();

  const float invd = 1.0f / (s_den0 + s_keptb);

  // ---- pass 3: write A row as bf16 (in place; all global reads done in pass 0)
  for (int j = tid; j < N_TOK; j += 256) {
    float ev = e[j];
    int b = (int)((ev - emin) * scale);
    b = (b < 0) ? 0 : ((b > NBUCK - 1) ? NBUCK - 1 : b);
    unsigned char c = bclass[b];
    float val = 0.f;
    if (c == 1 || (c == 2 && keepf[j])) val = ev * invd;
    arow[j] = f2bf(val);
  }
}

// ---------------------------------------------------------------------------
__global__ void cvt_bf(const float* __restrict__ src, u16* __restrict__ dst, int n)
{
  int i = blockIdx.x * 256 + threadIdx.x;
  if (i < n) dst[i] = f2bf(src[i]);
}

__global__ __launch_bounds__(256)
void tpose_bf(const float* __restrict__ X, u16* __restrict__ XT)
{
  __shared__ u16 tile[32][33];
  const int bc = blockIdx.x * 32;   // col in X (0..512)
  const int br = blockIdx.y * 32;   // row in X (0..4096)
  const int tx = threadIdx.x & 31, ty = threadIdx.x >> 5;
#pragma unroll
  for (int i = 0; i < 32; i += 8)
    tile[ty + i][tx] = f2bf(X[(size_t)(br + ty + i) * D_IN + bc + tx]);
  __syncthreads();
#pragma unroll
  for (int i = 0; i < 32; i += 8)
    XT[(size_t)(bc + ty + i) * N_TOK + br + tx] = tile[tx][ty + i];
}

__global__ __launch_bounds__(256)
void ln_kernel(const float* __restrict__ X, float* Z,
               const float* __restrict__ gamma, const float* __restrict__ beta)
{
  const int row = blockIdx.x, tid = threadIdx.x;
  const size_t base = (size_t)row * D_IN;
  __shared__ float red[4];
  __shared__ float s_mu, s_var;
  float y0 = X[base + tid] + Z[base + tid];
  float y1 = X[base + tid + 256] + Z[base + tid + 256];
  float s = y0 + y1;
  for (int o = 32; o; o >>= 1) s += __shfl_xor(s, o);
  if ((tid & 63) == 0) red[tid >> 6] = s;
  __syncthreads();
  if (tid == 0) s_mu = (red[0] + red[1] + red[2] + red[3]) * (1.f / D_IN);
  __syncthreads();
  const float mu = s_mu;
  float d0 = y0 - mu, d1 = y1 - mu;
  float v = d0 * d0 + d1 * d1;
  for (int o = 32; o; o >>= 1) v += __shfl_xor(v, o);
  if ((tid & 63) == 0) red[tid >> 6] = v;
  __syncthreads();
  if (tid == 0) s_var = (red[0] + red[1] + red[2] + red[3]) * (1.f / D_IN);
  __syncthreads();
  const float rs = rsqrtf(s_var + LN_EPS);
  Z[base + tid]       = d0 * rs * gamma[tid]       + beta[tid];
  Z[base + tid + 256] = d1 * rs * gamma[tid + 256] + beta[tid + 256];
}

// ---------------------------------------------------------------------------
extern "C" void kernel_launch(void* const* d_in, const int* in_sizes, int n_in,
                              void* d_out, int out_size, void* d_ws, size_t ws_size,
                              hipStream_t stream)
{
  const float* X     = (const float*)d_in[0];
  const float* W1    = (const float*)d_in[1];
  const float* W2    = (const float*)d_in[2];
  const float* W3    = (const float*)d_in[3];
  const float* U1    = (const float*)d_in[4];
  const float* U2    = (const float*)d_in[5];
  const float* U3    = (const float*)d_in[6];
  const float* gamma = (const float*)d_in[7];
  const float* beta  = (const float*)d_in[8];

  char* w = (char*)d_ws;
  float* S    = (float*)w;            w += (size_t)N_TOK * N_TOK * 4;   // 64 MB (scores f32 / A bf16 in-place)
  u16* Xbf    = (u16*)w;              w += (size_t)N_TOK * D_IN * 2;    // pristine bf16 X for Xf/Xb
  u16* Xa0    = (u16*)w;              w += (size_t)N_TOK * D_IN * 2;
  u16* Xa1    = (u16*)w;              w += (size_t)N_TOK * D_IN * 2;
  u16* XaT0   = (u16*)w;              w += (size_t)D_IN * N_TOK * 2;
  u16* XaT1   = (u16*)w;              w += (size_t)D_IN * N_TOK * 2;
  u16* hb     = (u16*)w;              w += (size_t)N_TOK * D_ATTN * 2;
  u16* qb     = (u16*)w;              w += (size_t)N_TOK * D_ATTN * 2;
  u16* kb     = (u16*)w;              w += (size_t)N_TOK * D_ATTN * 2;
  u16* W1b    = (u16*)w;              w += (size_t)D_ATTN * D_IN * 2;
  u16* W2b    = (u16*)w;              w += (size_t)D_ATTN * D_ATTN * 2;
  u16* W3b    = (u16*)w;              w += (size_t)D_ATTN * D_IN * 2;
  u16* U1b    = (u16*)w;              w += (size_t)2 * D_IN * D_IN * 2;
  u16* U2b    = (u16*)w;              w += (size_t)2 * D_IN * D_IN * 2;
  u16* U3b    = (u16*)w;              w += (size_t)2 * D_IN * D_IN * 2;

  float* Z = (float*)d_out;           // Z accumulator lives in d_out

  hipMemsetAsync(d_out, 0, (size_t)N_TOK * D_IN * 4, stream);

  const int nXD = N_TOK * D_IN;
  cvt_bf<<<(nXD + 255) / 256, 256, 0, stream>>>(X, Xbf, nXD);
  cvt_bf<<<(nXD + 255) / 256, 256, 0, stream>>>(X, Xa0, nXD);
  cvt_bf<<<(D_ATTN * D_IN + 255) / 256, 256, 0, stream>>>(W1, W1b, D_ATTN * D_IN);
  cvt_bf<<<(D_ATTN * D_ATTN + 255) / 256, 256, 0, stream>>>(W2, W2b, D_ATTN * D_ATTN);
  cvt_bf<<<(D_ATTN * D_IN + 255) / 256, 256, 0, stream>>>(W3, W3b, D_ATTN * D_IN);
  const int nU = 2 * D_IN * D_IN;
  cvt_bf<<<(nU + 255) / 256, 256, 0, stream>>>(U1, U1b, nU);
  cvt_bf<<<(nU + 255) / 256, 256, 0, stream>>>(U2, U2b, nU);
  cvt_bf<<<(nU + 255) / 256, 256, 0, stream>>>(U3, U3b, nU);
  tpose_bf<<<dim3(D_IN / 32, N_TOK / 32), 256, 0, stream>>>(X, XaT0);

  u16* XaC[2]  = {Xa0, Xa1};
  u16* XaTC[2] = {XaT0, XaT1};
  const int AMAX = N_TOK - 1;

  for (int n = 0; n < 2; ++n) {
    const int cur = n & 1, nxt = cur ^ 1;
    // h = tanh(Xa @ W1^T)  [4096,64]
    gemm_abt<1, 0><<<dim3(D_ATTN / 64, N_TOK / 64), 256, 0, stream>>>(
        XaC[cur], D_IN, AMAX, 0, W1b, D_IN, D_IN, nullptr, hb, nullptr, D_ATTN, 0);
    // k = Xa @ W3^T
    gemm_abt<2, 0><<<dim3(D_ATTN / 64, N_TOK / 64), 256, 0, stream>>>(
        XaC[cur], D_IN, AMAX, 0, W3b, D_IN, D_IN, nullptr, kb, nullptr, D_ATTN, 0);
    // q = h @ W2^T
    gemm_abt<2, 0><<<dim3(D_ATTN / 64, N_TOK / 64), 256, 0, stream>>>(
        hb, D_ATTN, AMAX, 0, W2b, D_ATTN, D_ATTN, nullptr, qb, nullptr, D_ATTN, 0);
    // S = q @ k^T (tau = 1)
    gemm_abt<0, 0><<<dim3(N_TOK / 64, N_TOK / 64), 256, 0, stream>>>(
        qb, D_ATTN, AMAX, 0, kb, D_ATTN, D_ATTN, S, nullptr, nullptr, N_TOK, 0);
    // softmax + top-p -> A (bf16, in-place over S)
    nucleus_kernel<<<N_TOK, 256, 0, stream>>>(S);
    // Xa_new = A @ Xa  (B-operand = XaT), dual write Xa_new and XaT_new
    gemm_abt<4, 0><<<dim3(D_IN / 64, N_TOK / 64), 256, 0, stream>>>(
        (u16*)S, 2 * N_TOK, AMAX, 0, XaTC[cur], N_TOK, N_TOK,
        nullptr, XaC[nxt], XaTC[nxt], D_IN, N_TOK);
    // Z += Xf @ U1[n]^T   (Xf row i = X[max(i-(n+1),0)])
    gemm_abt<3, 1><<<dim3(D_IN / 64, N_TOK / 64), 256, 0, stream>>>(
        Xbf, D_IN, AMAX, n + 1, U1b + (size_t)n * D_IN * D_IN, D_IN, D_IN,
        Z, nullptr, nullptr, D_IN, 0);
    // Z += Xb @ U2[n]^T   (Xb row i = X[min(i+(n+1),N-1)])
    gemm_abt<3, 2><<<dim3(D_IN / 64, N_TOK / 64), 256, 0, stream>>>(
        Xbf, D_IN, AMAX, n + 1, U2b + (size_t)n * D_IN * D_IN, D_IN, D_IN,
        Z, nullptr, nullptr, D_IN, 0);
    // Z += Xa_new @ U3[n]^T
    gemm_abt<3, 0><<<dim3(D_IN / 64, N_TOK / 64), 256, 0, stream>>>(
        XaC[nxt], D_IN, AMAX, 0, U3b + (size_t)n * D_IN * D_IN, D_IN, D_IN,
        Z, nullptr, nullptr, D_IN, 0);
  }

  // y = X + Z ; LayerNorm -> d_out (in place)
  ln_kernel<<<N_TOK, 256, 0, stream>>>(X, Z, gamma, beta);
}

// Round 2
// 714.919 us; speedup vs baseline: 1.2855x; 1.2855x over previous
//
#include <hip/hip_runtime.h>
#include <hip/hip_bf16.h>
#include <math.h>

typedef short bf16x8 __attribute__((ext_vector_type(8)));
typedef float f32x4 __attribute__((ext_vector_type(4)));
typedef unsigned short u16;

#define N_TOK  4096
#define D_IN   512
#define D_ATTN 64
#define NBUCK  4096
#define CAP    512
#define TOPP   0.9f
#define LN_EPS 1e-5f

__device__ __forceinline__ u16 f2bf(float f) {
  unsigned int u = __float_as_uint(f);
  return (u16)((u + 0x7FFFu + ((u >> 16) & 1u)) >> 16);
}

// ---------------------------------------------------------------------------
// Generic MFMA GEMM: C = rowmap(A) @ B^T
//   A: bf16 [M][K] row-major (lda), B: bf16 [Nc][K] row-major (ldb)
//   block tile 64x64, 4 waves (2x2), wave tile 32x32 = 2x2 mfma_16x16x32
// EPI: 0 store f32; 1 tanh->bf16; 2 bf16; 3 f32 +=; 4 bf16 dual (C and C^T)
// SMODE: 0 identity; 1 row->max(row-shift,0); 2 row->min(row+shift,amax)
// ---------------------------------------------------------------------------
template<int EPI, int SMODE>
__global__ __launch_bounds__(256)
void gemm_abt(const u16* __restrict__ A, int lda, int amax, int shift,
              const u16* __restrict__ B, int ldb, int K,
              float* __restrict__ Cf, u16* __restrict__ Cb,
              u16* __restrict__ CbT, int ldc, int ldct)
{
  const int tid  = threadIdx.x;
  const int wave = tid >> 6;
  const int lane = tid & 63;
  const int l15  = lane & 15;
  const int l4   = lane >> 4;          // 0..3
  const int brow = blockIdx.y << 6;
  const int bcol = blockIdx.x << 6;
  const int wr   = (wave >> 1) << 5;
  const int wc   = (wave & 1) << 5;

  const u16* Ap[2];
  const u16* Bp[2];
#pragma unroll
  for (int m = 0; m < 2; ++m) {
    int r = brow + wr + m * 16 + l15;
    if (SMODE == 1) { r = r - shift; if (r < 0) r = 0; }
    if (SMODE == 2) { r = r + shift; if (r > amax) r = amax; }
    Ap[m] = A + (size_t)r * lda + l4 * 8;
    int c = bcol + wc + m * 16 + l15;
    Bp[m] = B + (size_t)c * ldb + l4 * 8;
  }

  f32x4 acc[2][2];
#pragma unroll
  for (int m = 0; m < 2; ++m)
#pragma unroll
    for (int n = 0; n < 2; ++n) {
      acc[m][n][0] = 0.f; acc[m][n][1] = 0.f; acc[m][n][2] = 0.f; acc[m][n][3] = 0.f;
    }

  for (int k0 = 0; k0 < K; k0 += 32) {
    bf16x8 a0 = *(const bf16x8*)(Ap[0] + k0);
    bf16x8 a1 = *(const bf16x8*)(Ap[1] + k0);
    bf16x8 b0 = *(const bf16x8*)(Bp[0] + k0);
    bf16x8 b1 = *(const bf16x8*)(Bp[1] + k0);
    acc[0][0] = __builtin_amdgcn_mfma_f32_16x16x32_bf16(a0, b0, acc[0][0], 0, 0, 0);
    acc[0][1] = __builtin_amdgcn_mfma_f32_16x16x32_bf16(a0, b1, acc[0][1], 0, 0, 0);
    acc[1][0] = __builtin_amdgcn_mfma_f32_16x16x32_bf16(a1, b0, acc[1][0], 0, 0, 0);
    acc[1][1] = __builtin_amdgcn_mfma_f32_16x16x32_bf16(a1, b1, acc[1][1], 0, 0, 0);
  }

#pragma unroll
  for (int m = 0; m < 2; ++m)
#pragma unroll
    for (int n = 0; n < 2; ++n)
#pragma unroll
      for (int r = 0; r < 4; ++r) {
        const int row = brow + wr + m * 16 + l4 * 4 + r;   // C/D: col=lane&15, row=(lane>>4)*4+r
        const int col = bcol + wc + n * 16 + l15;
        const float v = acc[m][n][r];
        if (EPI == 0) Cf[(size_t)row * ldc + col] = v;
        if (EPI == 1) Cb[(size_t)row * ldc + col] = f2bf(tanhf(v));
        if (EPI == 2) Cb[(size_t)row * ldc + col] = f2bf(v);
        if (EPI == 3) Cf[(size_t)row * ldc + col] += v;
        if (EPI == 4) {
          u16 hv = f2bf(v);
          Cb [(size_t)row * ldc  + col] = hv;
          CbT[(size_t)col * ldct + row] = hv;
        }
      }
}

// ---------------------------------------------------------------------------
// Nucleus (top-p) row kernel. In: f32 scores row (4096). Out: bf16 A row
// written in-place over the same memory (first 8KB of the row's 16KB pitch).
// Row values held in registers (16/thread); histogram-based selection with
// parallel suffix scan; O(c^2) exact tie-aware refine of the boundary bucket.
// ---------------------------------------------------------------------------
__global__ __launch_bounds__(256)
void nucleus_kernel(float* __restrict__ S)
{
  const int row = blockIdx.x;
  const int tid = threadIdx.x;
  float* srow = S + (size_t)row * N_TOK;
  u16*   arow = (u16*)srow;            // bf16 view

  __shared__ float hist[NBUCK];        // 16 KB
  __shared__ float csum[256];          // 1 KB
  __shared__ float ge[CAP];            // 2 KB
  __shared__ int   gcol[CAP];          // 2 KB
  __shared__ unsigned char keepf[N_TOK]; // 4 KB (only boundary cols touched)
  __shared__ float red[8];
  __shared__ float s_smax, s_E, s_Abnd, s_keptb, s_emin, s_scale;
  __shared__ int   s_bstar, s_cnt;

  float ev[16];                        // this thread's 16 row elements
  // column of ev[4*i+r] is 1024*i + 4*tid + r

  // ---- pass 0: vectorized load, block max/min
  float lmax = -3.402823466e38f, lmin = 3.402823466e38f;
#pragma unroll
  for (int i = 0; i < 4; ++i) {
    float4 v = ((const float4*)srow)[tid + 256 * i];
    ev[4*i+0] = v.x; ev[4*i+1] = v.y; ev[4*i+2] = v.z; ev[4*i+3] = v.w;
    lmax = fmaxf(fmaxf(fmaxf(lmax, v.x), v.y), fmaxf(v.z, v.w));
    lmin = fminf(fminf(fminf(lmin, v.x), v.y), fminf(v.z, v.w));
  }
  for (int o = 32; o; o >>= 1) {
    lmax = fmaxf(lmax, __shfl_xor(lmax, o));
    lmin = fminf(lmin, __shfl_xor(lmin, o));
  }
  if ((tid & 63) == 0) { red[tid >> 6] = lmax; red[4 + (tid >> 6)] = lmin; }
#pragma unroll
  for (int i = 0; i < 4; ++i)
    ((float4*)hist)[tid + 256 * i] = make_float4(0.f, 0.f, 0.f, 0.f);
  __syncthreads();
  if (tid == 0) {
    float mx = fmaxf(fmaxf(red[0], red[1]), fmaxf(red[2], red[3]));
    float mn = fminf(fminf(red[4], red[5]), fminf(red[6], red[7]));
    s_smax = mx;
    float emin = __expf(mn - mx);
    s_emin = emin;
    s_scale = (float)NBUCK / fmaxf(1.0f - emin, 1e-30f);
    s_bstar = -1; s_cnt = 0; s_keptb = 0.f; s_Abnd = 0.f;
  }
  __syncthreads();
  const float smax = s_smax, emin = s_emin, scale = s_scale;

  // ---- pass 1: exp (in regs), exp-mass histogram, total E
  float lE = 0.f;
#pragma unroll
  for (int r = 0; r < 16; ++r) {
    float e = __expf(ev[r] - smax);
    ev[r] = e;
    lE += e;
    int b = (int)((e - emin) * scale);
    b = (b < 0) ? 0 : ((b > NBUCK - 1) ? NBUCK - 1 : b);
    atomicAdd(&hist[b], e);
  }
  for (int o = 32; o; o >>= 1) lE += __shfl_xor(lE, o);
  if ((tid & 63) == 0) red[tid >> 6] = lE;
  __syncthreads();
  if (tid == 0) s_E = red[0] + red[1] + red[2] + red[3];
  __syncthreads();
  const float T = TOPP * s_E;

  // ---- pass 2: parallel suffix scan over 256 chunk sums, find boundary
  float ch = 0.f;
  const int b0 = tid << 4;
#pragma unroll
  for (int b = b0; b < b0 + 16; ++b) ch += hist[b];
  csum[tid] = ch;
  __syncthreads();
  if (tid < 64) {
    float c0 = csum[4*tid], c1 = csum[4*tid+1], c2 = csum[4*tid+2], c3 = csum[4*tid+3];
    float s4 = c0 + c1 + c2 + c3;
    float v = s4;
#pragma unroll
    for (int o = 1; o < 64; o <<= 1) {
      float t = __shfl_down(v, o);
      if (tid + o < 64) v += t;
    }
    float above = v - s4;              // mass in chunks strictly above 4*tid+3
    csum[4*tid+3] = above;
    csum[4*tid+2] = above + c3;
    csum[4*tid+1] = above + c3 + c2;
    csum[4*tid+0] = above + c3 + c2 + c1;
  }
  __syncthreads();
  {
    float Arun = csum[tid];            // mass strictly above my top bucket
    for (int b = b0 + 15; b >= b0; --b) {
      float bm = hist[b];
      if (Arun < T && Arun + bm >= T) { s_bstar = b; s_Abnd = Arun; }
      Arun += bm;
    }
  }
  __syncthreads();
  const int bstar = s_bstar;           // unique; fully-kept mass == s_Abnd

  // ---- gather boundary-bucket elements
#pragma unroll
  for (int r = 0; r < 16; ++r) {
    float e = ev[r];
    int b = (int)((e - emin) * scale);
    b = (b < 0) ? 0 : ((b > NBUCK - 1) ? NBUCK - 1 : b);
    if (b == bstar) {
      int i = atomicAdd(&s_cnt, 1);
      if (i < CAP) { ge[i] = e; gcol[i] = ((r >> 2) << 10) + (tid << 2) + (r & 3); }
    }
  }
  __syncthreads();
  const int cnt = s_cnt;
  const float Abnd = s_Abnd;

  // ---- refine boundary: exact prefix mass with stable-tie rule (idx order)
  float lk = 0.f;
  if (cnt <= CAP) {
    for (int i = tid; i < cnt; i += 256) {
      float ei = ge[i]; int ci = gcol[i];
      float m = Abnd;
      for (int l = 0; l < cnt; ++l) {
        float el = ge[l];
        if (el > ei || (el == ei && gcol[l] < ci)) m += el;
      }
      unsigned char kp = (m < T) ? 1 : 0;
      keepf[ci] = kp;
      if (kp) lk += ei;
    }
  } else {
    // pathological fallback (near-degenerate rows): re-read row from global
#pragma unroll
    for (int r = 0; r < 16; ++r) {
      float ej = ev[r];
      int b = (int)((ej - emin) * scale);
      b = (b < 0) ? 0 : ((b > NBUCK - 1) ? NBUCK - 1 : b);
      if (b != bstar) continue;
      int cj = ((r >> 2) << 10) + (tid << 2) + (r & 3);
      float m = Abnd;
      for (int l = 0; l < N_TOK; ++l) {
        float el = __expf(srow[l] - smax);
        int bl = (int)((el - emin) * scale);
        bl = (bl < 0) ? 0 : ((bl > NBUCK - 1) ? NBUCK - 1 : bl);
        if (bl == bstar && (el > ej || (el == ej && l < cj))) m += el;
      }
      unsigned char kp = (m < T) ? 1 : 0;
      keepf[cj] = kp;
      if (kp) lk += ej;
    }
  }
  for (int o = 32; o; o >>= 1) lk += __shfl_xor(lk, o);
  if ((tid & 63) == 0) red[tid >> 6] = lk;
  __syncthreads();
  if (tid == 0) s_keptb = red[0] + red[1] + red[2] + red[3];
  __syncthreads();

  const float invd = 1.0f / (s_Abnd + s_keptb);

  // ---- pass 3: write A row as bf16 (in place; no global f32 reads remain)
#pragma unroll
  for (int i = 0; i < 4; ++i) {
    ushort4 o4;
#pragma unroll
    for (int r = 0; r < 4; ++r) {
      float e = ev[4*i + r];
      int b = (int)((e - emin) * scale);
      b = (b < 0) ? 0 : ((b > NBUCK - 1) ? NBUCK - 1 : b);
      float val = 0.f;
      if (b > bstar) val = e * invd;
      else if (b == bstar && keepf[(i << 10) + (tid << 2) + r]) val = e * invd;
      ((u16*)&o4)[r] = f2bf(val);
    }
    ((ushort4*)arow)[tid + 256 * i] = o4;
  }
}

// ---------------------------------------------------------------------------
__global__ void cvt_bf4(const float* __restrict__ src, u16* __restrict__ d1,
                        u16* __restrict__ d2, int n4)
{
  int i = blockIdx.x * 256 + threadIdx.x;
  if (i < n4) {
    float4 v = ((const float4*)src)[i];
    ushort4 o;
    o.x = f2bf(v.x); o.y = f2bf(v.y); o.z = f2bf(v.z); o.w = f2bf(v.w);
    ((ushort4*)d1)[i] = o;
    if (d2) ((ushort4*)d2)[i] = o;
  }
}

__global__ __launch_bounds__(256)
void tpose_bf(const float* __restrict__ X, u16* __restrict__ XT)
{
  __shared__ u16 tile[32][33];
  const int bc = blockIdx.x * 32;   // col in X (0..512)
  const int br = blockIdx.y * 32;   // row in X (0..4096)
  const int tx = threadIdx.x & 31, ty = threadIdx.x >> 5;
#pragma unroll
  for (int i = 0; i < 32; i += 8)
    tile[ty + i][tx] = f2bf(X[(size_t)(br + ty + i) * D_IN + bc + tx]);
  __syncthreads();
#pragma unroll
  for (int i = 0; i < 32; i += 8)
    XT[(size_t)(bc + ty + i) * N_TOK + br + tx] = tile[tx][ty + i];
}

__global__ __launch_bounds__(256)
void ln_kernel(const float* __restrict__ X, float* Z,
               const float* __restrict__ gamma, const float* __restrict__ beta)
{
  const int row = blockIdx.x, tid = threadIdx.x;
  const size_t base = (size_t)row * D_IN;
  __shared__ float red[4];
  __shared__ float s_mu, s_var;
  float y0 = X[base + tid] + Z[base + tid];
  float y1 = X[base + tid + 256] + Z[base + tid + 256];
  float s = y0 + y1;
  for (int o = 32; o; o >>= 1) s += __shfl_xor(s, o);
  if ((tid & 63) == 0) red[tid >> 6] = s;
  __syncthreads();
  if (tid == 0) s_mu = (red[0] + red[1] + red[2] + red[3]) * (1.f / D_IN);
  __syncthreads();
  const float mu = s_mu;
  float d0 = y0 - mu, d1 = y1 - mu;
  float v = d0 * d0 + d1 * d1;
  for (int o = 32; o; o >>= 1) v += __shfl_xor(v, o);
  if ((tid & 63) == 0) red[tid >> 6] = v;
  __syncthreads();
  if (tid == 0) s_var = (red[0] + red[1] + red[2] + red[3]) * (1.f / D_IN);
  __syncthreads();
  const float rs = rsqrtf(s_var + LN_EPS);
  Z[base + tid]       = d0 * rs * gamma[tid]       + beta[tid];
  Z[base + tid + 256] = d1 * rs * gamma[tid + 256] + beta[tid + 256];
}

// ---------------------------------------------------------------------------
extern "C" void kernel_launch(void* const* d_in, const int* in_sizes, int n_in,
                              void* d_out, int out_size, void* d_ws, size_t ws_size,
                              hipStream_t stream)
{
  const float* X     = (const float*)d_in[0];
  const float* W1    = (const float*)d_in[1];
  const float* W2    = (const float*)d_in[2];
  const float* W3    = (const float*)d_in[3];
  const float* U1    = (const float*)d_in[4];
  const float* U2    = (const float*)d_in[5];
  const float* U3    = (const float*)d_in[6];
  const float* gamma = (const float*)d_in[7];
  const float* beta  = (const float*)d_in[8];

  char* w = (char*)d_ws;
  float* S    = (float*)w;            w += (size_t)N_TOK * N_TOK * 4;   // 64 MB (scores f32 / A bf16 in-place)
  u16* Xbf    = (u16*)w;              w += (size_t)N_TOK * D_IN * 2;    // pristine bf16 X for Xf/Xb
  u16* Xa0    = (u16*)w;              w += (size_t)N_TOK * D_IN * 2;
  u16* Xa1    = (u16*)w;              w += (size_t)N_TOK * D_IN * 2;
  u16* XaT0   = (u16*)w;              w += (size_t)D_IN * N_TOK * 2;
  u16* XaT1   = (u16*)w;              w += (size_t)D_IN * N_TOK * 2;
  u16* hb     = (u16*)w;              w += (size_t)N_TOK * D_ATTN * 2;
  u16* qb     = (u16*)w;              w += (size_t)N_TOK * D_ATTN * 2;
  u16* kb     = (u16*)w;              w += (size_t)N_TOK * D_ATTN * 2;
  u16* W1b    = (u16*)w;              w += (size_t)D_ATTN * D_IN * 2;
  u16* W2b    = (u16*)w;              w += (size_t)D_ATTN * D_ATTN * 2;
  u16* W3b    = (u16*)w;              w += (size_t)D_ATTN * D_IN * 2;
  u16* U1b    = (u16*)w;              w += (size_t)2 * D_IN * D_IN * 2;
  u16* U2b    = (u16*)w;              w += (size_t)2 * D_IN * D_IN * 2;
  u16* U3b    = (u16*)w;              w += (size_t)2 * D_IN * D_IN * 2;

  float* Z = (float*)d_out;           // Z accumulator lives in d_out

  hipMemsetAsync(d_out, 0, (size_t)N_TOK * D_IN * 4, stream);

  const int nXD4 = N_TOK * D_IN / 4;
  cvt_bf4<<<(nXD4 + 255) / 256, 256, 0, stream>>>(X, Xbf, Xa0, nXD4);
  cvt_bf4<<<(D_ATTN * D_IN / 4 + 255) / 256, 256, 0, stream>>>(W1, W1b, nullptr, D_ATTN * D_IN / 4);
  cvt_bf4<<<(D_ATTN * D_ATTN / 4 + 255) / 256, 256, 0, stream>>>(W2, W2b, nullptr, D_ATTN * D_ATTN / 4);
  cvt_bf4<<<(D_ATTN * D_IN / 4 + 255) / 256, 256, 0, stream>>>(W3, W3b, nullptr, D_ATTN * D_IN / 4);
  const int nU4 = 2 * D_IN * D_IN / 4;
  cvt_bf4<<<(nU4 + 255) / 256, 256, 0, stream>>>(U1, U1b, nullptr, nU4);
  cvt_bf4<<<(nU4 + 255) / 256, 256, 0, stream>>>(U2, U2b, nullptr, nU4);
  cvt_bf4<<<(nU4 + 255) / 256, 256, 0, stream>>>(U3, U3b, nullptr, nU4);
  tpose_bf<<<dim3(D_IN / 32, N_TOK / 32), 256, 0, stream>>>(X, XaT0);

  u16* XaC[2]  = {Xa0, Xa1};
  u16* XaTC[2] = {XaT0, XaT1};
  const int AMAX = N_TOK - 1;

  for (int n = 0; n < 2; ++n) {
    const int cur = n & 1, nxt = cur ^ 1;
    // h = tanh(Xa @ W1^T)  [4096,64]
    gemm_abt<1, 0><<<dim3(D_ATTN / 64, N_TOK / 64), 256, 0, stream>>>(
        XaC[cur], D_IN, AMAX, 0, W1b, D_IN, D_IN, nullptr, hb, nullptr, D_ATTN, 0);
    // k = Xa @ W3^T
    gemm_abt<2, 0><<<dim3(D_ATTN / 64, N_TOK / 64), 256, 0, stream>>>(
        XaC[cur], D_IN, AMAX, 0, W3b, D_IN, D_IN, nullptr, kb, nullptr, D_ATTN, 0);
    // q = h @ W2^T
    gemm_abt<2, 0><<<dim3(D_ATTN / 64, N_TOK / 64), 256, 0, stream>>>(
        hb, D_ATTN, AMAX, 0, W2b, D_ATTN, D_ATTN, nullptr, qb, nullptr, D_ATTN, 0);
    // S = q @ k^T (tau = 1)
    gemm_abt<0, 0><<<dim3(N_TOK / 64, N_TOK / 64), 256, 0, stream>>>(
        qb, D_ATTN, AMAX, 0, kb, D_ATTN, D_ATTN, S, nullptr, nullptr, N_TOK, 0);
    // softmax + top-p -> A (bf16, in-place over S)
    nucleus_kernel<<<N_TOK, 256, 0, stream>>>(S);
    // Xa_new = A @ Xa  (B-operand = XaT), dual write Xa_new and XaT_new
    gemm_abt<4, 0><<<dim3(D_IN / 64, N_TOK / 64), 256, 0, stream>>>(
        (u16*)S, 2 * N_TOK, AMAX, 0, XaTC[cur], N_TOK, N_TOK,
        nullptr, XaC[nxt], XaTC[nxt], D_IN, N_TOK);
    // Z += Xf @ U1[n]^T   (Xf row i = X[max(i-(n+1),0)])
    gemm_abt<3, 1><<<dim3(D_IN / 64, N_TOK / 64), 256, 0, stream>>>(
        Xbf, D_IN, AMAX, n + 1, U1b + (size_t)n * D_IN * D_IN, D_IN, D_IN,
        Z, nullptr, nullptr, D_IN, 0);
    // Z += Xb @ U2[n]^T   (Xb row i = X[min(i+(n+1),N-1)])
    gemm_abt<3, 2><<<dim3(D_IN / 64, N_TOK / 64), 256, 0, stream>>>(
        Xbf, D_IN, AMAX, n + 1, U2b + (size_t)n * D_IN * D_IN, D_IN, D_IN,
        Z, nullptr, nullptr, D_IN, 0);
    // Z += Xa_new @ U3[n]^T
    gemm_abt<3, 0><<<dim3(D_IN / 64, N_TOK / 64), 256, 0, stream>>>(
        XaC[nxt], D_IN, AMAX, 0, U3b + (size_t)n * D_IN * D_IN, D_IN, D_IN,
        Z, nullptr, nullptr, D_IN, 0);
  }

  // y = X + Z ; LayerNorm -> d_out (in place)
  ln_kernel<<<N_TOK, 256, 0, stream>>>(X, Z, gamma, beta);
}

// Round 3
// 573.866 us; speedup vs baseline: 1.6015x; 1.2458x over previous
//
#include <hip/hip_runtime.h>
#include <hip/hip_bf16.h>
#include <math.h>

typedef short bf16x8 __attribute__((ext_vector_type(8)));
typedef float f32x4 __attribute__((ext_vector_type(4)));
typedef unsigned short u16;

#define N_TOK  4096
#define D_IN   512
#define D_ATTN 64
#define NBUCK  4096
#define CAP    512
#define TOPP   0.9f
#define LN_EPS 1e-5f
#define AMAXV  (N_TOK - 1)

__device__ __forceinline__ u16 f2bf(float f) {
  unsigned int u = __float_as_uint(f);
  return (u16)((u + 0x7FFFu + ((u >> 16) & 1u)) >> 16);
}

__device__ __forceinline__ void gload16(const u16* g, u16* l) {
  __builtin_amdgcn_global_load_lds(
      (const __attribute__((address_space(1))) unsigned int*)g,
      (__attribute__((address_space(3))) unsigned int*)l, 16, 0, 0);
}

// ---------------------------------------------------------------------------
// gemm128: C = sum_seg rowmap(A_s) @ B_s^T.  BM=128, BN=64, BK=64.
// A_s: bf16 [M][K] row-major; B_s: bf16 [N][K] row-major.
// 256 threads = 4 waves (2x2), wave tile 64x32 = 4x2 frags of 16x16x32.
// Double-buffered LDS staging via global_load_lds (linear dest) with
// XOR chunk swizzle (inverse-swizzled global src, swizzled ds_read).
// Per-iter: STAGE(next) -> ds_read+MFMA(cur) -> vmcnt(0) -> s_barrier.
// EPI: 0 f32 store; 1 tanh->bf16; 2 bf16; 3 f32 +=; 4 bf16 dual (C, C^T)
// rowmap: r = clamp(r + sh, 0, N_TOK-1)  (sh=0 identity, +/- chain priors)
// ---------------------------------------------------------------------------
template<int EPI, int NSEG, int KSEG>
__global__ __launch_bounds__(256)
void gemm128(const u16* __restrict__ A0, int lda0, int sh0, const u16* __restrict__ B0, int ldb0,
             const u16* __restrict__ A1, int lda1, int sh1, const u16* __restrict__ B1, int ldb1,
             const u16* __restrict__ A2, int lda2, int sh2, const u16* __restrict__ B2, int ldb2,
             float* __restrict__ Cf, u16* __restrict__ Cb, u16* __restrict__ CbT,
             int ldc, int ldct)
{
  __shared__ u16 sA[2][128 * 64];   // 32 KB
  __shared__ u16 sB[2][64 * 64];    // 16 KB

  const int tid  = threadIdx.x;
  const int wave = tid >> 6;
  const int lane = tid & 63;
  const int l15  = lane & 15;
  const int l4   = lane >> 4;
  const int brow = blockIdx.y << 7;
  const int bcol = blockIdx.x << 6;
  const int wr64 = (wave >> 1) << 6;
  const int wc32 = (wave & 1) << 5;

  constexpr int IPSEG = KSEG >> 6;
  constexpr int TOTAL = NSEG * IPSEG;

  auto stage = [&](int buf, int it) {
    int seg = (NSEG == 1) ? 0 : (it / IPSEG);
    int kk  = (NSEG == 1) ? (it << 6) : ((it % IPSEG) << 6);
    const u16 *Ab, *Bb; int la, lb, sh;
    if (seg == 0)      { Ab = A0; la = lda0; sh = sh0; Bb = B0; lb = ldb0; }
    else if (seg == 1) { Ab = A1; la = lda1; sh = sh1; Bb = B1; lb = ldb1; }
    else               { Ab = A2; la = lda2; sh = sh2; Bb = B2; lb = ldb2; }
#pragma unroll
    for (int q = 0; q < 4; ++q) {              // A tile: 128x64 = 16 KB
      int idx = q * 256 + tid;
      int row = idx >> 3;
      int chunk = (idx & 7) ^ (row & 7);       // inverse swizzle on source
      int r = brow + row + sh;
      r = (r < 0) ? 0 : ((r > AMAXV) ? AMAXV : r);
      gload16(Ab + (size_t)r * la + kk + chunk * 8, &sA[buf][idx * 8]);
    }
#pragma unroll
    for (int q = 0; q < 2; ++q) {              // B tile: 64x64 = 8 KB
      int idx = q * 256 + tid;
      int row = idx >> 3;
      int chunk = (idx & 7) ^ (row & 7);
      gload16(Bb + (size_t)(bcol + row) * lb + kk + chunk * 8, &sB[buf][idx * 8]);
    }
  };

  f32x4 acc[4][2];
#pragma unroll
  for (int m = 0; m < 4; ++m)
#pragma unroll
    for (int n = 0; n < 2; ++n) {
      acc[m][n][0] = 0.f; acc[m][n][1] = 0.f; acc[m][n][2] = 0.f; acc[m][n][3] = 0.f;
    }

  stage(0, 0);
  asm volatile("s_waitcnt vmcnt(0)" ::: "memory");
  __builtin_amdgcn_s_barrier();

  for (int i = 0; i < TOTAL; ++i) {
    const int c = i & 1;
    if (i + 1 < TOTAL) stage(c ^ 1, i + 1);
#pragma unroll
    for (int ks = 0; ks < 2; ++ks) {
      bf16x8 af[4], bfr[2];
#pragma unroll
      for (int m = 0; m < 4; ++m) {
        int ar = wr64 + m * 16 + l15;
        af[m] = *(const bf16x8*)&sA[c][ar * 64 + (((ks << 2) + l4) ^ (ar & 7)) * 8];
      }
#pragma unroll
      for (int n = 0; n < 2; ++n) {
        int br = wc32 + n * 16 + l15;
        bfr[n] = *(const bf16x8*)&sB[c][br * 64 + (((ks << 2) + l4) ^ (br & 7)) * 8];
      }
#pragma unroll
      for (int m = 0; m < 4; ++m)
#pragma unroll
        for (int n = 0; n < 2; ++n)
          acc[m][n] = __builtin_amdgcn_mfma_f32_16x16x32_bf16(af[m], bfr[n], acc[m][n], 0, 0, 0);
    }
    asm volatile("s_waitcnt vmcnt(0)" ::: "memory");
    __builtin_amdgcn_s_barrier();
  }

#pragma unroll
  for (int m = 0; m < 4; ++m)
#pragma unroll
    for (int n = 0; n < 2; ++n)
#pragma unroll
      for (int r = 0; r < 4; ++r) {
        const int row = brow + wr64 + m * 16 + l4 * 4 + r;
        const int col = bcol + wc32 + n * 16 + l15;
        const float v = acc[m][n][r];
        if (EPI == 0) Cf[(size_t)row * ldc + col] = v;
        if (EPI == 1) Cb[(size_t)row * ldc + col] = f2bf(tanhf(v));
        if (EPI == 2) Cb[(size_t)row * ldc + col] = f2bf(v);
        if (EPI == 3) Cf[(size_t)row * ldc + col] += v;
        if (EPI == 4) {
          u16 hv = f2bf(v);
          Cb [(size_t)row * ldc  + col] = hv;
          CbT[(size_t)col * ldct + row] = hv;
        }
      }
}

// ---------------------------------------------------------------------------
// Nucleus (top-p) row kernel (unchanged from round 2).
// ---------------------------------------------------------------------------
__global__ __launch_bounds__(256)
void nucleus_kernel(float* __restrict__ S)
{
  const int row = blockIdx.x;
  const int tid = threadIdx.x;
  float* srow = S + (size_t)row * N_TOK;
  u16*   arow = (u16*)srow;            // bf16 view

  __shared__ float hist[NBUCK];
  __shared__ float csum[256];
  __shared__ float ge[CAP];
  __shared__ int   gcol[CAP];
  __shared__ unsigned char keepf[N_TOK];
  __shared__ float red[8];
  __shared__ float s_smax, s_E, s_Abnd, s_keptb, s_emin, s_scale;
  __shared__ int   s_bstar, s_cnt;

  float ev[16];

  float lmax = -3.402823466e38f, lmin = 3.402823466e38f;
#pragma unroll
  for (int i = 0; i < 4; ++i) {
    float4 v = ((const float4*)srow)[tid + 256 * i];
    ev[4*i+0] = v.x; ev[4*i+1] = v.y; ev[4*i+2] = v.z; ev[4*i+3] = v.w;
    lmax = fmaxf(fmaxf(fmaxf(lmax, v.x), v.y), fmaxf(v.z, v.w));
    lmin = fminf(fminf(fminf(lmin, v.x), v.y), fminf(v.z, v.w));
  }
  for (int o = 32; o; o >>= 1) {
    lmax = fmaxf(lmax, __shfl_xor(lmax, o));
    lmin = fminf(lmin, __shfl_xor(lmin, o));
  }
  if ((tid & 63) == 0) { red[tid >> 6] = lmax; red[4 + (tid >> 6)] = lmin; }
#pragma unroll
  for (int i = 0; i < 4; ++i)
    ((float4*)hist)[tid + 256 * i] = make_float4(0.f, 0.f, 0.f, 0.f);
  __syncthreads();
  if (tid == 0) {
    float mx = fmaxf(fmaxf(red[0], red[1]), fmaxf(red[2], red[3]));
    float mn = fminf(fminf(red[4], red[5]), fminf(red[6], red[7]));
    s_smax = mx;
    float emin = __expf(mn - mx);
    s_emin = emin;
    s_scale = (float)NBUCK / fmaxf(1.0f - emin, 1e-30f);
    s_bstar = -1; s_cnt = 0; s_keptb = 0.f; s_Abnd = 0.f;
  }
  __syncthreads();
  const float smax = s_smax, emin = s_emin, scale = s_scale;

  float lE = 0.f;
#pragma unroll
  for (int r = 0; r < 16; ++r) {
    float e = __expf(ev[r] - smax);
    ev[r] = e;
    lE += e;
    int b = (int)((e - emin) * scale);
    b = (b < 0) ? 0 : ((b > NBUCK - 1) ? NBUCK - 1 : b);
    atomicAdd(&hist[b], e);
  }
  for (int o = 32; o; o >>= 1) lE += __shfl_xor(lE, o);
  if ((tid & 63) == 0) red[tid >> 6] = lE;
  __syncthreads();
  if (tid == 0) s_E = red[0] + red[1] + red[2] + red[3];
  __syncthreads();
  const float T = TOPP * s_E;

  float ch = 0.f;
  const int b0 = tid << 4;
#pragma unroll
  for (int b = b0; b < b0 + 16; ++b) ch += hist[b];
  csum[tid] = ch;
  __syncthreads();
  if (tid < 64) {
    float c0 = csum[4*tid], c1 = csum[4*tid+1], c2 = csum[4*tid+2], c3 = csum[4*tid+3];
    float s4 = c0 + c1 + c2 + c3;
    float v = s4;
#pragma unroll
    for (int o = 1; o < 64; o <<= 1) {
      float t = __shfl_down(v, o);
      if (tid + o < 64) v += t;
    }
    float above = v - s4;
    csum[4*tid+3] = above;
    csum[4*tid+2] = above + c3;
    csum[4*tid+1] = above + c3 + c2;
    csum[4*tid+0] = above + c3 + c2 + c1;
  }
  __syncthreads();
  {
    float Arun = csum[tid];
    for (int b = b0 + 15; b >= b0; --b) {
      float bm = hist[b];
      if (Arun < T && Arun + bm >= T) { s_bstar = b; s_Abnd = Arun; }
      Arun += bm;
    }
  }
  __syncthreads();
  const int bstar = s_bstar;

#pragma unroll
  for (int r = 0; r < 16; ++r) {
    float e = ev[r];
    int b = (int)((e - emin) * scale);
    b = (b < 0) ? 0 : ((b > NBUCK - 1) ? NBUCK - 1 : b);
    if (b == bstar) {
      int i = atomicAdd(&s_cnt, 1);
      if (i < CAP) { ge[i] = e; gcol[i] = ((r >> 2) << 10) + (tid << 2) + (r & 3); }
    }
  }
  __syncthreads();
  const int cnt = s_cnt;
  const float Abnd = s_Abnd;

  float lk = 0.f;
  if (cnt <= CAP) {
    for (int i = tid; i < cnt; i += 256) {
      float ei = ge[i]; int ci = gcol[i];
      float m = Abnd;
      for (int l = 0; l < cnt; ++l) {
        float el = ge[l];
        if (el > ei || (el == ei && gcol[l] < ci)) m += el;
      }
      unsigned char kp = (m < T) ? 1 : 0;
      keepf[ci] = kp;
      if (kp) lk += ei;
    }
  } else {
#pragma unroll
    for (int r = 0; r < 16; ++r) {
      float ej = ev[r];
      int b = (int)((ej - emin) * scale);
      b = (b < 0) ? 0 : ((b > NBUCK - 1) ? NBUCK - 1 : b);
      if (b != bstar) continue;
      int cj = ((r >> 2) << 10) + (tid << 2) + (r & 3);
      float m = Abnd;
      for (int l = 0; l < N_TOK; ++l) {
        float el = __expf(srow[l] - smax);
        int bl = (int)((el - emin) * scale);
        bl = (bl < 0) ? 0 : ((bl > NBUCK - 1) ? NBUCK - 1 : bl);
        if (bl == bstar && (el > ej || (el == ej && l < cj))) m += el;
      }
      unsigned char kp = (m < T) ? 1 : 0;
      keepf[cj] = kp;
      if (kp) lk += ej;
    }
  }
  for (int o = 32; o; o >>= 1) lk += __shfl_xor(lk, o);
  if ((tid & 63) == 0) red[tid >> 6] = lk;
  __syncthreads();
  if (tid == 0) s_keptb = red[0] + red[1] + red[2] + red[3];
  __syncthreads();

  const float invd = 1.0f / (s_Abnd + s_keptb);

#pragma unroll
  for (int i = 0; i < 4; ++i) {
    ushort4 o4;
#pragma unroll
    for (int r = 0; r < 4; ++r) {
      float e = ev[4*i + r];
      int b = (int)((e - emin) * scale);
      b = (b < 0) ? 0 : ((b > NBUCK - 1) ? NBUCK - 1 : b);
      float val = 0.f;
      if (b > bstar) val = e * invd;
      else if (b == bstar && keepf[(i << 10) + (tid << 2) + r]) val = e * invd;
      ((u16*)&o4)[r] = f2bf(val);
    }
    ((ushort4*)arow)[tid + 256 * i] = o4;
  }
}

// ---------------------------------------------------------------------------
__global__ void cvt_bf4(const float* __restrict__ src, u16* __restrict__ d1,
                        u16* __restrict__ d2, int n4)
{
  int i = blockIdx.x * 256 + threadIdx.x;
  if (i < n4) {
    float4 v = ((const float4*)src)[i];
    ushort4 o;
    o.x = f2bf(v.x); o.y = f2bf(v.y); o.z = f2bf(v.z); o.w = f2bf(v.w);
    ((ushort4*)d1)[i] = o;
    if (d2) ((ushort4*)d2)[i] = o;
  }
}

__global__ __launch_bounds__(256)
void tpose_bf(const float* __restrict__ X, u16* __restrict__ XT)
{
  __shared__ u16 tile[32][33];
  const int bc = blockIdx.x * 32;
  const int br = blockIdx.y * 32;
  const int tx = threadIdx.x & 31, ty = threadIdx.x >> 5;
#pragma unroll
  for (int i = 0; i < 32; i += 8)
    tile[ty + i][tx] = f2bf(X[(size_t)(br + ty + i) * D_IN + bc + tx]);
  __syncthreads();
#pragma unroll
  for (int i = 0; i < 32; i += 8)
    XT[(size_t)(bc + ty + i) * N_TOK + br + tx] = tile[tx][ty + i];
}

__global__ __launch_bounds__(256)
void ln_kernel(const float* __restrict__ X, float* Z,
               const float* __restrict__ gamma, const float* __restrict__ beta)
{
  const int row = blockIdx.x, tid = threadIdx.x;
  const size_t base = (size_t)row * D_IN;
  __shared__ float red[4];
  __shared__ float s_mu, s_var;
  float y0 = X[base + tid] + Z[base + tid];
  float y1 = X[base + tid + 256] + Z[base + tid + 256];
  float s = y0 + y1;
  for (int o = 32; o; o >>= 1) s += __shfl_xor(s, o);
  if ((tid & 63) == 0) red[tid >> 6] = s;
  __syncthreads();
  if (tid == 0) s_mu = (red[0] + red[1] + red[2] + red[3]) * (1.f / D_IN);
  __syncthreads();
  const float mu = s_mu;
  float d0 = y0 - mu, d1 = y1 - mu;
  float v = d0 * d0 + d1 * d1;
  for (int o = 32; o; o >>= 1) v += __shfl_xor(v, o);
  if ((tid & 63) == 0) red[tid >> 6] = v;
  __syncthreads();
  if (tid == 0) s_var = (red[0] + red[1] + red[2] + red[3]) * (1.f / D_IN);
  __syncthreads();
  const float rs = rsqrtf(s_var + LN_EPS);
  Z[base + tid]       = d0 * rs * gamma[tid]       + beta[tid];
  Z[base + tid + 256] = d1 * rs * gamma[tid + 256] + beta[tid + 256];
}

// ---------------------------------------------------------------------------
extern "C" void kernel_launch(void* const* d_in, const int* in_sizes, int n_in,
                              void* d_out, int out_size, void* d_ws, size_t ws_size,
                              hipStream_t stream)
{
  const float* X     = (const float*)d_in[0];
  const float* W1    = (const float*)d_in[1];
  const float* W2    = (const float*)d_in[2];
  const float* W3    = (const float*)d_in[3];
  const float* U1    = (const float*)d_in[4];
  const float* U2    = (const float*)d_in[5];
  const float* U3    = (const float*)d_in[6];
  const float* gamma = (const float*)d_in[7];
  const float* beta  = (const float*)d_in[8];

  char* w = (char*)d_ws;
  float* S    = (float*)w;            w += (size_t)N_TOK * N_TOK * 4;   // 64 MB
  u16* Xbf    = (u16*)w;              w += (size_t)N_TOK * D_IN * 2;
  u16* Xa0    = (u16*)w;              w += (size_t)N_TOK * D_IN * 2;
  u16* Xa1    = (u16*)w;              w += (size_t)N_TOK * D_IN * 2;
  u16* XaT0   = (u16*)w;              w += (size_t)D_IN * N_TOK * 2;
  u16* XaT1   = (u16*)w;              w += (size_t)D_IN * N_TOK * 2;
  u16* hb     = (u16*)w;              w += (size_t)N_TOK * D_ATTN * 2;
  u16* qb     = (u16*)w;              w += (size_t)N_TOK * D_ATTN * 2;
  u16* kb     = (u16*)w;              w += (size_t)N_TOK * D_ATTN * 2;
  u16* W1b    = (u16*)w;              w += (size_t)D_ATTN * D_IN * 2;
  u16* W2b    = (u16*)w;              w += (size_t)D_ATTN * D_ATTN * 2;
  u16* W3b    = (u16*)w;              w += (size_t)D_ATTN * D_IN * 2;
  u16* U1b    = (u16*)w;              w += (size_t)2 * D_IN * D_IN * 2;
  u16* U2b    = (u16*)w;              w += (size_t)2 * D_IN * D_IN * 2;
  u16* U3b    = (u16*)w;              w += (size_t)2 * D_IN * D_IN * 2;

  float* Z = (float*)d_out;

  hipMemsetAsync(d_out, 0, (size_t)N_TOK * D_IN * 4, stream);

  const int nXD4 = N_TOK * D_IN / 4;
  cvt_bf4<<<(nXD4 + 255) / 256, 256, 0, stream>>>(X, Xbf, Xa0, nXD4);
  cvt_bf4<<<(D_ATTN * D_IN / 4 + 255) / 256, 256, 0, stream>>>(W1, W1b, nullptr, D_ATTN * D_IN / 4);
  cvt_bf4<<<(D_ATTN * D_ATTN / 4 + 255) / 256, 256, 0, stream>>>(W2, W2b, nullptr, D_ATTN * D_ATTN / 4);
  cvt_bf4<<<(D_ATTN * D_IN / 4 + 255) / 256, 256, 0, stream>>>(W3, W3b, nullptr, D_ATTN * D_IN / 4);
  const int nU4 = 2 * D_IN * D_IN / 4;
  cvt_bf4<<<(nU4 + 255) / 256, 256, 0, stream>>>(U1, U1b, nullptr, nU4);
  cvt_bf4<<<(nU4 + 255) / 256, 256, 0, stream>>>(U2, U2b, nullptr, nU4);
  cvt_bf4<<<(nU4 + 255) / 256, 256, 0, stream>>>(U3, U3b, nullptr, nU4);
  tpose_bf<<<dim3(D_IN / 32, N_TOK / 32), 256, 0, stream>>>(X, XaT0);

  u16* XaC[2]  = {Xa0, Xa1};
  u16* XaTC[2] = {XaT0, XaT1};

  for (int n = 0; n < 2; ++n) {
    const int cur = n & 1, nxt = cur ^ 1;
    const size_t uoff = (size_t)n * D_IN * D_IN;
    // h = tanh(Xa @ W1^T)  [4096,64]
    gemm128<1, 1, D_IN><<<dim3(1, 32), 256, 0, stream>>>(
        XaC[cur], D_IN, 0, W1b, D_IN,
        nullptr, 0, 0, nullptr, 0, nullptr, 0, 0, nullptr, 0,
        nullptr, hb, nullptr, D_ATTN, 0);
    // k = Xa @ W3^T
    gemm128<2, 1, D_IN><<<dim3(1, 32), 256, 0, stream>>>(
        XaC[cur], D_IN, 0, W3b, D_IN,
        nullptr, 0, 0, nullptr, 0, nullptr, 0, 0, nullptr, 0,
        nullptr, kb, nullptr, D_ATTN, 0);
    // q = h @ W2^T
    gemm128<2, 1, D_ATTN><<<dim3(1, 32), 256, 0, stream>>>(
        hb, D_ATTN, 0, W2b, D_ATTN,
        nullptr, 0, 0, nullptr, 0, nullptr, 0, 0, nullptr, 0,
        nullptr, qb, nullptr, D_ATTN, 0);
    // S = q @ k^T
    gemm128<0, 1, D_ATTN><<<dim3(64, 32), 256, 0, stream>>>(
        qb, D_ATTN, 0, kb, D_ATTN,
        nullptr, 0, 0, nullptr, 0, nullptr, 0, 0, nullptr, 0,
        S, nullptr, nullptr, N_TOK, 0);
    // softmax + top-p -> A (bf16, in-place over S, row pitch 2*N_TOK)
    nucleus_kernel<<<N_TOK, 256, 0, stream>>>(S);
    // Xa_new = A @ Xa : A lda=8192, B = XaT cur; dual-write Xa_new, XaT_new
    gemm128<4, 1, N_TOK><<<dim3(8, 32), 256, 0, stream>>>(
        (const u16*)S, 2 * N_TOK, 0, XaTC[cur], N_TOK,
        nullptr, 0, 0, nullptr, 0, nullptr, 0, 0, nullptr, 0,
        nullptr, XaC[nxt], XaTC[nxt], D_IN, N_TOK);
    // Z += Xf@U1^T + Xb@U2^T + Xa_new@U3^T   (fused 3-segment)
    gemm128<3, 3, D_IN><<<dim3(8, 32), 256, 0, stream>>>(
        Xbf, D_IN, -(n + 1), U1b + uoff, D_IN,
        Xbf, D_IN,  (n + 1), U2b + uoff, D_IN,
        XaC[nxt], D_IN, 0,   U3b + uoff, D_IN,
        Z, nullptr, nullptr, D_IN, 0);
  }

  // y = X + Z ; LayerNorm (in place over Z = d_out)
  ln_kernel<<<N_TOK, 256, 0, stream>>>(X, Z, gamma, beta);
}